// Round 1
// baseline (1150.299 us; speedup 1.0000x reference)
//
#include <hip/hip_runtime.h>
#include <math.h>

#define DIM   1024
#define NH    16
#define HD    64
#define BATCH 2
#define SEQ   2048
#define ROWS  (BATCH*SEQ)   // 4096

// ---------------------------------------------------------------------------
// fp32 tiled GEMM body: C[M,1024] = A[M,1024] @ W[1024,1024] (+bias) (+RoPE)
// tile 128x128, BK=16, 256 threads, 8x8 microtile (4+4 split rows/cols)
// ---------------------------------------------------------------------------
__device__ __forceinline__ void gemm_body(const float* __restrict__ A,
                                          const float* __restrict__ W,
                                          const float* __restrict__ bias,
                                          float* __restrict__ C,
                                          const float* __restrict__ fc,
                                          const float* __restrict__ fs,
                                          bool rope)
{
    __shared__ float lds_a[128][20];   // [row][k], stride 80B (16B-aligned)
    __shared__ float lds_b[16][132];   // [k][col], stride 528B (16B-aligned)

    const int tid = threadIdx.x;
    const int tx  = tid & 15, ty = tid >> 4;
    const int n0  = blockIdx.x * 128;
    const int m0  = blockIdx.y * 128;

    const int arow = tid >> 2, akc = (tid & 3) << 2;   // A: 128 rows x 16k, 2 float4/thread
    const int bkk  = tid >> 5, bcf = tid & 31;         // B: 16k x 128 cols, 2 float4/thread

    float acc[2][2][4][4] = {};

    for (int k0 = 0; k0 < DIM; k0 += 16) {
        __syncthreads();   // previous iter's LDS reads complete
        float4 a0 = *(const float4*)&A[(m0 + arow     ) * DIM + k0 + akc];
        float4 a1 = *(const float4*)&A[(m0 + arow + 64) * DIM + k0 + akc];
        float4 b0 = *(const float4*)&W[(k0 + bkk    ) * DIM + n0 + bcf * 4];
        float4 b1 = *(const float4*)&W[(k0 + bkk + 8) * DIM + n0 + bcf * 4];
        *(float4*)&lds_a[arow     ][akc] = a0;
        *(float4*)&lds_a[arow + 64][akc] = a1;
        *(float4*)&lds_b[bkk    ][bcf * 4] = b0;
        *(float4*)&lds_b[bkk + 8][bcf * 4] = b1;
        __syncthreads();

        #pragma unroll
        for (int kk4 = 0; kk4 < 16; kk4 += 4) {
            float ar[2][4][4], br[2][4][4];
            #pragma unroll
            for (int j = 0; j < 4; j++) {
                *(float4*)ar[0][j] = *(const float4*)&lds_a[     ty * 4 + j][kk4];
                *(float4*)ar[1][j] = *(const float4*)&lds_a[64 + ty * 4 + j][kk4];
            }
            #pragma unroll
            for (int kk = 0; kk < 4; kk++) {
                *(float4*)br[0][kk] = *(const float4*)&lds_b[kk4 + kk][     tx * 4];
                *(float4*)br[1][kk] = *(const float4*)&lds_b[kk4 + kk][64 + tx * 4];
            }
            #pragma unroll
            for (int rh = 0; rh < 2; rh++)
            #pragma unroll
            for (int ch = 0; ch < 2; ch++)
            #pragma unroll
            for (int j = 0; j < 4; j++)
            #pragma unroll
            for (int kk = 0; kk < 4; kk++)
            #pragma unroll
            for (int i = 0; i < 4; i++)
                acc[rh][ch][j][i] = fmaf(ar[rh][j][kk], br[ch][kk][i], acc[rh][ch][j][i]);
        }
    }

    #pragma unroll
    for (int rh = 0; rh < 2; rh++)
    #pragma unroll
    for (int ch = 0; ch < 2; ch++)
    #pragma unroll
    for (int j = 0; j < 4; j++) {
        const int r  = m0 + rh * 64 + ty * 4 + j;
        const int c0 = n0 + ch * 64 + tx * 4;
        float o0 = acc[rh][ch][j][0], o1 = acc[rh][ch][j][1];
        float o2 = acc[rh][ch][j][2], o3 = acc[rh][ch][j][3];
        if (bias) {
            o0 += bias[c0]; o1 += bias[c0 + 1]; o2 += bias[c0 + 2]; o3 += bias[c0 + 3];
        }
        if (rope) {
            const int s  = r & (SEQ - 1);
            const int i0 = (c0 & (HD - 1)) >> 1;          // pair index within head
            const float ca = fc[s * 32 + i0],     sa = fs[s * 32 + i0];
            const float cb = fc[s * 32 + i0 + 1], sb = fs[s * 32 + i0 + 1];
            float xr = o0, xi = o1;
            o0 = xr * ca - xi * sa; o1 = xr * sa + xi * ca;
            xr = o2; xi = o3;
            o2 = xr * cb - xi * sb; o3 = xr * sb + xi * cb;
        }
        *(float4*)&C[r * DIM + c0] = make_float4(o0, o1, o2, o3);
    }
}

__global__ __launch_bounds__(256) void qkv_gemm_kernel(
    const float* __restrict__ x,
    const float* __restrict__ wq, const float* __restrict__ wk, const float* __restrict__ wv,
    const float* __restrict__ bq, const float* __restrict__ bk, const float* __restrict__ bv,
    const float* __restrict__ fc, const float* __restrict__ fs,
    float* __restrict__ q, float* __restrict__ k, float* __restrict__ v)
{
    const int z = blockIdx.z;
    const float* W  = (z == 0) ? wq : (z == 1) ? wk : wv;
    const float* bb = (z == 0) ? bq : (z == 1) ? bk : bv;
    float*       o  = (z == 0) ? q  : (z == 1) ? k  : v;
    gemm_body(x, W, bb, o, fc, fs, z < 2);
}

__global__ __launch_bounds__(256) void out_gemm_kernel(
    const float* __restrict__ a, const float* __restrict__ wo, float* __restrict__ c)
{
    gemm_body(a, wo, nullptr, c, nullptr, nullptr, false);
}

// ---------------------------------------------------------------------------
// fp32 flash attention: one block per (b, h, 64 q-rows), K/V tiles of 64.
// 256 threads, 4x4 S-microtile, online softmax via 16-lane shfl_xor reduce.
// lkp is shared between the K tile and the P tile (4-barrier schedule).
// ---------------------------------------------------------------------------
__global__ __launch_bounds__(256) void flash_kernel(
    const float* __restrict__ Q, const float* __restrict__ K, const float* __restrict__ V,
    const float* __restrict__ mask, float* __restrict__ O)
{
    __shared__ float lq [64][68];
    __shared__ float lkp[64][68];   // K tile, then reused for P tile
    __shared__ float lv [64][68];

    const int tid = threadIdx.x;
    const int tx  = tid & 15, ty = tid >> 4;
    const int q0  = blockIdx.x * 64;
    const int h   = blockIdx.y, b = blockIdx.z;
    const int base = (b * SEQ) * DIM + h * HD;

    #pragma unroll
    for (int i = 0; i < 4; i++) {
        const int f = tid + i * 256, row = f >> 4, dc = (f & 15) << 2;
        *(float4*)&lq[row][dc] = *(const float4*)&Q[base + (q0 + row) * DIM + dc];
    }

    float m_r[4], l_r[4], acc[4][4] = {};
    #pragma unroll
    for (int j = 0; j < 4; j++) { m_r[j] = -INFINITY; l_r[j] = 0.f; }

    for (int k0 = 0; k0 < SEQ; k0 += 64) {
        __syncthreads();   // (1) previous PV done: lkp/lv free
        #pragma unroll
        for (int i = 0; i < 4; i++) {
            const int f = tid + i * 256, row = f >> 4, dc = (f & 15) << 2;
            *(float4*)&lkp[row][dc] = *(const float4*)&K[base + (k0 + row) * DIM + dc];
            *(float4*)&lv [row][dc] = *(const float4*)&V[base + (k0 + row) * DIM + dc];
        }
        __syncthreads();   // (2) K,V visible

        float s[4][4] = {};
        #pragma unroll
        for (int d0 = 0; d0 < HD; d0 += 4) {
            float qa[4][4], kb[4][4];
            #pragma unroll
            for (int j = 0; j < 4; j++) *(float4*)qa[j] = *(const float4*)&lq [ty * 4 + j][d0];
            #pragma unroll
            for (int i = 0; i < 4; i++) *(float4*)kb[i] = *(const float4*)&lkp[tx * 4 + i][d0];
            #pragma unroll
            for (int j = 0; j < 4; j++)
            #pragma unroll
            for (int i = 0; i < 4; i++)
            #pragma unroll
            for (int dd = 0; dd < 4; dd++)
                s[j][i] = fmaf(qa[j][dd], kb[i][dd], s[j][i]);
        }

        #pragma unroll
        for (int j = 0; j < 4; j++) {
            const float4 mk = *(const float4*)&mask[(q0 + ty * 4 + j) * SEQ + k0 + tx * 4];
            s[j][0] = s[j][0] * 0.125f + mk.x;
            s[j][1] = s[j][1] * 0.125f + mk.y;
            s[j][2] = s[j][2] * 0.125f + mk.z;
            s[j][3] = s[j][3] * 0.125f + mk.w;
            float mt = fmaxf(fmaxf(s[j][0], s[j][1]), fmaxf(s[j][2], s[j][3]));
            #pragma unroll
            for (int off = 1; off < 16; off <<= 1) mt = fmaxf(mt, __shfl_xor(mt, off));
            const float mn = fmaxf(m_r[j], mt);
            const float sc = __expf(m_r[j] - mn);
            float ps = 0.f;
            #pragma unroll
            for (int i = 0; i < 4; i++) { s[j][i] = __expf(s[j][i] - mn); ps += s[j][i]; }
            #pragma unroll
            for (int off = 1; off < 16; off <<= 1) ps += __shfl_xor(ps, off);
            l_r[j] = l_r[j] * sc + ps;
            m_r[j] = mn;
            #pragma unroll
            for (int i = 0; i < 4; i++) acc[j][i] *= sc;
        }

        __syncthreads();   // (3) everyone done reading lkp as K
        #pragma unroll
        for (int j = 0; j < 4; j++)
            *(float4*)&lkp[ty * 4 + j][tx * 4] = make_float4(s[j][0], s[j][1], s[j][2], s[j][3]);
        __syncthreads();   // (4) P visible

        #pragma unroll
        for (int kk0 = 0; kk0 < 64; kk0 += 4) {
            float pr[4][4], vr[4][4];
            #pragma unroll
            for (int j = 0; j < 4; j++)  *(float4*)pr[j]  = *(const float4*)&lkp[ty * 4 + j][kk0];
            #pragma unroll
            for (int kk = 0; kk < 4; kk++) *(float4*)vr[kk] = *(const float4*)&lv[kk0 + kk][tx * 4];
            #pragma unroll
            for (int j = 0; j < 4; j++)
            #pragma unroll
            for (int kk = 0; kk < 4; kk++)
            #pragma unroll
            for (int i = 0; i < 4; i++)
                acc[j][i] = fmaf(pr[j][kk], vr[kk][i], acc[j][i]);
        }
    }

    #pragma unroll
    for (int j = 0; j < 4; j++) {
        const float inv = 1.f / l_r[j];
        *(float4*)&O[base + (q0 + ty * 4 + j) * DIM + tx * 4] =
            make_float4(acc[j][0] * inv, acc[j][1] * inv, acc[j][2] * inv, acc[j][3] * inv);
    }
}

// ---------------------------------------------------------------------------
extern "C" void kernel_launch(void* const* d_in, const int* in_sizes, int n_in,
                              void* d_out, int out_size, void* d_ws, size_t ws_size,
                              hipStream_t stream)
{
    const float* x    = (const float*)d_in[0];
    const float* mask = (const float*)d_in[1];
    const float* fc   = (const float*)d_in[2];
    const float* fs   = (const float*)d_in[3];
    const float* wq   = (const float*)d_in[4];
    const float* bq   = (const float*)d_in[5];
    const float* wk   = (const float*)d_in[6];
    const float* bk   = (const float*)d_in[7];
    const float* wv   = (const float*)d_in[8];
    const float* bv   = (const float*)d_in[9];
    const float* wo   = (const float*)d_in[10];
    float* out = (float*)d_out;

    float* q  = (float*)d_ws;            // 4096x1024
    float* k  = q  + ROWS * DIM;
    float* v  = k  + ROWS * DIM;
    float* ao = v  + ROWS * DIM;         // attention output

    dim3 gQKV(DIM / 128, ROWS / 128, 3);
    qkv_gemm_kernel<<<gQKV, 256, 0, stream>>>(x, wq, wk, wv, bq, bk, bv, fc, fs, q, k, v);

    dim3 gF(SEQ / 64, NH, BATCH);
    flash_kernel<<<gF, 256, 0, stream>>>(q, k, v, mask, ao);

    dim3 gO(DIM / 128, ROWS / 128, 1);
    out_gemm_kernel<<<gO, 256, 0, stream>>>(ao, wo, out);
}

// Round 2
// 390.938 us; speedup vs baseline: 2.9424x; 2.9424x over previous
//
#include <hip/hip_runtime.h>
#include <math.h>
#include <stdint.h>

#define DIM   1024
#define NH    16
#define HD    64
#define BATCH 2
#define SEQ   2048
#define ROWS  (BATCH*SEQ)   // 4096

typedef __attribute__((ext_vector_type(8))) short short8;   // 8 x bf16 (4 VGPR)
typedef __attribute__((ext_vector_type(4))) float f32x4;

// ---- bf16 split helpers (RNE) ----------------------------------------------
__device__ __forceinline__ unsigned short f2bf(float f) {
    union { float f; unsigned u; } x; x.f = f;
    unsigned r = x.u + 0x7FFFu + ((x.u >> 16) & 1u);
    return (unsigned short)(r >> 16);
}
__device__ __forceinline__ float bf2f(unsigned short h) {
    union { unsigned u; float f; } x; x.u = ((unsigned)h) << 16;
    return x.f;
}

#define MFMA(a,b,c) __builtin_amdgcn_mfma_f32_16x16x32_bf16((a),(b),(c),0,0,0)

// ---------------------------------------------------------------------------
// split x -> Xh, Xl bf16 planes (same layout)
// ---------------------------------------------------------------------------
__global__ __launch_bounds__(256) void splitx_kernel(
    const float* __restrict__ x, unsigned short* __restrict__ xh, unsigned short* __restrict__ xl)
{
    const size_t i = ((size_t)blockIdx.x * 256 + threadIdx.x) * 4;
    const float4 v = *(const float4*)&x[i];
    ushort4 h, l;
    h.x = f2bf(v.x); l.x = f2bf(v.x - bf2f(h.x));
    h.y = f2bf(v.y); l.y = f2bf(v.y - bf2f(h.y));
    h.z = f2bf(v.z); l.z = f2bf(v.z - bf2f(h.z));
    h.w = f2bf(v.w); l.w = f2bf(v.w - bf2f(h.w));
    *(ushort4*)&xh[i] = h;
    *(ushort4*)&xl[i] = l;
}

// ---------------------------------------------------------------------------
// transpose + split the four 1024x1024 weights: WT[n][k] hi/lo bf16
// grid (16,16,4): x = n-tile, y = k-tile, z = which weight
// ---------------------------------------------------------------------------
__global__ __launch_bounds__(256) void splitw_kernel(
    const float* __restrict__ w0, const float* __restrict__ w1,
    const float* __restrict__ w2, const float* __restrict__ w3,
    unsigned short* __restrict__ wth, unsigned short* __restrict__ wtl)
{
    __shared__ float tile[64][68];
    const int z = blockIdx.z;
    const float* W = (z == 0) ? w0 : (z == 1) ? w1 : (z == 2) ? w2 : w3;
    unsigned short* th = wth + (size_t)z * DIM * DIM;
    unsigned short* tl = wtl + (size_t)z * DIM * DIM;
    const int k0 = blockIdx.y * 64, n0 = blockIdx.x * 64;
    const int tr = threadIdx.x >> 4, tc = (threadIdx.x & 15) * 4;
    #pragma unroll
    for (int p = 0; p < 4; ++p) {
        const float4 v = *(const float4*)&W[(size_t)(k0 + tr + p*16) * DIM + n0 + tc];
        *(float4*)&tile[tr + p*16][tc] = v;
    }
    __syncthreads();
    #pragma unroll
    for (int p = 0; p < 4; ++p) {
        const int n = tr + p*16;
        ushort4 hv, lv;
        float v0 = tile[tc+0][n], v1 = tile[tc+1][n], v2 = tile[tc+2][n], v3 = tile[tc+3][n];
        hv.x = f2bf(v0); lv.x = f2bf(v0 - bf2f(hv.x));
        hv.y = f2bf(v1); lv.y = f2bf(v1 - bf2f(hv.y));
        hv.z = f2bf(v2); lv.z = f2bf(v2 - bf2f(hv.z));
        hv.w = f2bf(v3); lv.w = f2bf(v3 - bf2f(hv.w));
        *(ushort4*)&th[(size_t)(n0 + n) * DIM + k0 + tc] = hv;
        *(ushort4*)&tl[(size_t)(n0 + n) * DIM + k0 + tc] = lv;
    }
}

// ---------------------------------------------------------------------------
// split-bf16 3-term MFMA GEMM: C[4096,1024] = A @ W (+bias) (+RoPE)
// A planes [m][k] bf16, W planes transposed [n][k] bf16 (TN). 128x128, BK=32.
// MODE 0: QKV (z selects W/bias/epilogue)   MODE 1: out-proj (fp32 store)
// ---------------------------------------------------------------------------
template<int MODE>
__global__ __launch_bounds__(256, 2) void gemm3_kernel(
    const unsigned short* __restrict__ Ah, const unsigned short* __restrict__ Al,
    const unsigned short* __restrict__ Wh0, const unsigned short* __restrict__ Wl0,
    const unsigned short* __restrict__ Wh1, const unsigned short* __restrict__ Wl1,
    const unsigned short* __restrict__ Wh2, const unsigned short* __restrict__ Wl2,
    const float* __restrict__ b0, const float* __restrict__ b1, const float* __restrict__ b2,
    const float* __restrict__ fc, const float* __restrict__ fs,
    unsigned short* __restrict__ q_h, unsigned short* __restrict__ q_l,
    unsigned short* __restrict__ k_h, unsigned short* __restrict__ k_l,
    unsigned short* __restrict__ vt_h, unsigned short* __restrict__ vt_l,
    float* __restrict__ outf)
{
    __shared__ __align__(16) unsigned short lah[128*32], lal[128*32];
    __shared__ __align__(16) unsigned short lbh[128*32], lbl[128*32];

    const int tid = threadIdx.x;
    const int lane = tid & 63;
    const int lx = lane & 15, lg = lane >> 4;
    const int wv = tid >> 6, wm = wv >> 1, wn = wv & 1;
    const int n0 = blockIdx.x * 128, m0 = blockIdx.y * 128;
    const int z = (MODE == 0) ? blockIdx.z : 3;

    const unsigned short *Wh, *Wl;
    const float* bias;
    if (MODE == 0) {
        Wh = (z == 0) ? Wh0 : (z == 1) ? Wh1 : Wh2;
        Wl = (z == 0) ? Wl0 : (z == 1) ? Wl1 : Wl2;
        bias = (z == 0) ? b0 : (z == 1) ? b1 : b2;
    } else { Wh = Wh0; Wl = Wl0; bias = nullptr; }

    const int sr  = tid >> 2;          // staging row 0..63 (and +64)
    const int scb = (tid & 3) * 16;    // byte col within 64B row

    f32x4 acc[4][4] = {};
    uint4 ra0, ra1, rl0, rl1, rb0, rb1, rb2, rb3;

    auto loadA = [&](int k0i) {
        const size_t a0 = ((size_t)(m0 + sr)      * DIM + k0i) * 2 + scb;
        const size_t a1 = ((size_t)(m0 + sr + 64) * DIM + k0i) * 2 + scb;
        ra0 = *(const uint4*)((const char*)Ah + a0);
        ra1 = *(const uint4*)((const char*)Ah + a1);
        rl0 = *(const uint4*)((const char*)Al + a0);
        rl1 = *(const uint4*)((const char*)Al + a1);
        const size_t bb0 = ((size_t)(n0 + sr)      * DIM + k0i) * 2 + scb;
        const size_t bb1 = ((size_t)(n0 + sr + 64) * DIM + k0i) * 2 + scb;
        rb0 = *(const uint4*)((const char*)Wh + bb0);
        rb1 = *(const uint4*)((const char*)Wh + bb1);
        rb2 = *(const uint4*)((const char*)Wl + bb0);
        rb3 = *(const uint4*)((const char*)Wl + bb1);
    };

    loadA(0);
    for (int k0i = 0; k0i < DIM; k0i += 32) {
        __syncthreads();
        {
            const int o0 = sr*64 + scb, o1 = (sr + 64)*64 + scb;
            *(uint4*)((char*)lah + o0) = ra0; *(uint4*)((char*)lah + o1) = ra1;
            *(uint4*)((char*)lal + o0) = rl0; *(uint4*)((char*)lal + o1) = rl1;
            *(uint4*)((char*)lbh + o0) = rb0; *(uint4*)((char*)lbh + o1) = rb1;
            *(uint4*)((char*)lbl + o0) = rb2; *(uint4*)((char*)lbl + o1) = rb3;
        }
        __syncthreads();
        if (k0i + 32 < DIM) loadA(k0i + 32);

        short8 afh[4], afl[4], bfh[4], bfl[4];
        #pragma unroll
        for (int i = 0; i < 4; ++i) {
            const int ar = wm*64 + i*16 + lx;
            afh[i] = *(const short8*)((const char*)lah + ar*64 + lg*16);
            afl[i] = *(const short8*)((const char*)lal + ar*64 + lg*16);
            const int br = wn*64 + i*16 + lx;
            bfh[i] = *(const short8*)((const char*)lbh + br*64 + lg*16);
            bfl[i] = *(const short8*)((const char*)lbl + br*64 + lg*16);
        }
        #pragma unroll
        for (int i = 0; i < 4; ++i)
        #pragma unroll
        for (int jn = 0; jn < 4; ++jn) {
            acc[i][jn] = MFMA(afh[i], bfh[jn], acc[i][jn]);
            acc[i][jn] = MFMA(afh[i], bfl[jn], acc[i][jn]);
            acc[i][jn] = MFMA(afl[i], bfh[jn], acc[i][jn]);
        }
    }

    // epilogue
    #pragma unroll
    for (int i = 0; i < 4; ++i) {
        const int tokbase = m0 + wm*64 + i*16 + lg*4;
        #pragma unroll
        for (int jn = 0; jn < 4; ++jn) {
            const int c = n0 + wn*64 + jn*16 + lx;
            float bv = (MODE == 0) ? bias[c] : 0.f;
            float vj[4];
            #pragma unroll
            for (int j = 0; j < 4; ++j) vj[j] = acc[i][jn][j] + bv;
            if (MODE == 0 && z < 2) {
                const int i0 = (c & 63) >> 1;
                #pragma unroll
                for (int j = 0; j < 4; ++j) {
                    const int s = (tokbase + j) & (SEQ - 1);
                    const float cv = fc[s*32 + i0], sv = fs[s*32 + i0];
                    const float pv = __shfl_xor(vj[j], 1);
                    vj[j] = (c & 1) ? (pv*sv + vj[j]*cv) : (vj[j]*cv - pv*sv);
                }
            }
            if (MODE == 1) {
                #pragma unroll
                for (int j = 0; j < 4; ++j)
                    outf[(size_t)(tokbase + j) * DIM + c] = vj[j];
            } else if (z < 2) {
                unsigned short* oh = z ? k_h : q_h;
                unsigned short* ol = z ? k_l : q_l;
                #pragma unroll
                for (int j = 0; j < 4; ++j) {
                    const unsigned short hi = f2bf(vj[j]);
                    oh[(size_t)(tokbase + j) * DIM + c] = hi;
                    ol[(size_t)(tokbase + j) * DIM + c] = f2bf(vj[j] - bf2f(hi));
                }
            } else {
                const int bb = tokbase >> 11, s0 = tokbase & (SEQ - 1);
                const int hh = c >> 6, d = c & 63;
                const size_t vb = ((size_t)(bb*NH + hh) * HD + d) * SEQ + s0;
                ushort4 hv, lv;
                #pragma unroll
                for (int j = 0; j < 4; ++j) {
                    const unsigned short hi = f2bf(vj[j]);
                    ((unsigned short*)&hv)[j] = hi;
                    ((unsigned short*)&lv)[j] = f2bf(vj[j] - bf2f(hi));
                }
                *(ushort4*)&vt_h[vb] = hv;
                *(ushort4*)&vt_l[vb] = lv;
            }
        }
    }
}

// ---------------------------------------------------------------------------
// MFMA flash attention. 512 threads = 8 waves; Q-tile 128 (16 q-rows/wave),
// K/V tiles 64 double-buffered in swizzled LDS; swapped QK^T (mfma(K,Q));
// wave-private P in LDS; 3-term split everywhere. One barrier per K-tile.
// grid (16, NH, BATCH)
// ---------------------------------------------------------------------------
__global__ __launch_bounds__(512, 2) void attn_kernel(
    const unsigned short* __restrict__ Qh, const unsigned short* __restrict__ Ql,
    const unsigned short* __restrict__ Kh, const unsigned short* __restrict__ Kl,
    const unsigned short* __restrict__ Vth, const unsigned short* __restrict__ Vtl,
    const float* __restrict__ mask,
    unsigned short* __restrict__ AOh, unsigned short* __restrict__ AOl)
{
    __shared__ __align__(16) unsigned short kbh[2][64*64], kbl[2][64*64];
    __shared__ __align__(16) unsigned short vbh[2][64*64], vbl[2][64*64];
    __shared__ __align__(16) unsigned short pbh[8][16*64], pbl[8][16*64];

    const int tid = threadIdx.x;
    const int w = tid >> 6, lane = tid & 63;
    const int lx = lane & 15, lg = lane >> 4;
    const int qblk = blockIdx.x * 128;
    const int h = blockIdx.y, b = blockIdx.z;

    const int qrow = qblk + w*16 + lx;                 // this lane's softmax row
    const size_t qtok = (size_t)b * SEQ + qrow;

    short8 qf[2][2];                                   // [plane][ks]
    {
        const size_t base = qtok * DIM + h*HD + lg*8;
        qf[0][0] = *(const short8*)&Qh[base];
        qf[0][1] = *(const short8*)&Qh[base + 32];
        qf[1][0] = *(const short8*)&Ql[base];
        qf[1][1] = *(const short8*)&Ql[base + 32];
    }

    float m_st = -INFINITY, l_st = 0.f;
    f32x4 acc[4] = {};

    const int sr  = tid >> 3;                          // staging row 0..63
    const int scb = (tid & 7) * 16;                    // byte col within 128B row
    const int swz_w = sr*128 + (scb ^ ((sr&1)<<6) ^ ((sr&2)<<4));

    uint4 sa, sc, sd, se;
    auto stage_load = [&](int t) {
        const size_t kr = ((size_t)b*SEQ + t*64 + sr) * DIM + h*HD;
        sa = *(const uint4*)((const char*)Kh + kr*2 + scb);
        sc = *(const uint4*)((const char*)Kl + kr*2 + scb);
        const size_t vr = ((size_t)(b*NH + h) * HD + sr) * SEQ + t*64;
        sd = *(const uint4*)((const char*)Vth + vr*2 + scb);
        se = *(const uint4*)((const char*)Vtl + vr*2 + scb);
    };
    auto stage_write = [&](int buf) {
        *(uint4*)((char*)&kbh[buf][0] + swz_w) = sa;
        *(uint4*)((char*)&kbl[buf][0] + swz_w) = sc;
        *(uint4*)((char*)&vbh[buf][0] + swz_w) = sd;
        *(uint4*)((char*)&vbl[buf][0] + swz_w) = se;
    };

    stage_load(0);
    stage_write(0);
    __syncthreads();

    const float* mrow_base = mask + (size_t)qrow * SEQ;

    for (int t = 0; t < SEQ/64; ++t) {
        const int cur = t & 1;
        if (t < SEQ/64 - 1) stage_load(t + 1);

        // --- S^T = K·Q^T (3-term) ---
        f32x4 st[4] = {};
        const char* khb = (const char*)&kbh[cur][0];
        const char* klb = (const char*)&kbl[cur][0];
        #pragma unroll
        for (int ks = 0; ks < 2; ++ks) {
            #pragma unroll
            for (int mf = 0; mf < 4; ++mf) {
                const int row = mf*16 + lx;
                const int off = row*128 + ((ks*64 + lg*16) ^ ((row&1)<<6) ^ ((row&2)<<4));
                const short8 akh = *(const short8*)(khb + off);
                const short8 akl = *(const short8*)(klb + off);
                st[mf] = MFMA(akh, qf[0][ks], st[mf]);
                st[mf] = MFMA(akh, qf[1][ks], st[mf]);
                st[mf] = MFMA(akl, qf[0][ks], st[mf]);
            }
        }

        // --- online softmax (lane owns q-column lx of this wave) ---
        float p[4][4];
        float mx = -INFINITY;
        const float* mrow = mrow_base + t*64;
        #pragma unroll
        for (int mf = 0; mf < 4; ++mf) {
            const float4 mk = *(const float4*)&mrow[mf*16 + lg*4];
            p[mf][0] = st[mf][0]*0.125f + mk.x;
            p[mf][1] = st[mf][1]*0.125f + mk.y;
            p[mf][2] = st[mf][2]*0.125f + mk.z;
            p[mf][3] = st[mf][3]*0.125f + mk.w;
            mx = fmaxf(mx, fmaxf(fmaxf(p[mf][0], p[mf][1]), fmaxf(p[mf][2], p[mf][3])));
        }
        mx = fmaxf(mx, __shfl_xor(mx, 16));
        mx = fmaxf(mx, __shfl_xor(mx, 32));
        const float mnew = fmaxf(m_st, mx);
        const float scl = __expf(m_st - mnew);
        m_st = mnew;

        float ps = 0.f;
        #pragma unroll
        for (int mf = 0; mf < 4; ++mf) {
            unsigned hw0, hw1, lw0, lw1;
            #pragma unroll
            for (int j = 0; j < 4; ++j) {
                const float e = __expf(p[mf][j] - mnew);
                ps += e;
                const unsigned short hi = f2bf(e);
                const unsigned short lo = f2bf(e - bf2f(hi));
                if (j == 0) { hw0 = hi; lw0 = lo; }
                else if (j == 1) { hw0 |= (unsigned)hi << 16; lw0 |= (unsigned)lo << 16; }
                else if (j == 2) { hw1 = hi; lw1 = lo; }
                else { hw1 |= (unsigned)hi << 16; lw1 |= (unsigned)lo << 16; }
            }
            const int off = lx*128 + ((mf*32 + lg*8) ^ ((lx&1)<<6) ^ ((lx&2)<<4));
            *(uint2*)((char*)&pbh[w][0] + off) = make_uint2(hw0, hw1);
            *(uint2*)((char*)&pbl[w][0] + off) = make_uint2(lw0, lw1);
        }
        ps += __shfl_xor(ps, 16);
        ps += __shfl_xor(ps, 32);
        l_st = l_st * scl + ps;

        // rescale accumulator rows (q = w*16 + lg*4 + j)
        float fj[4];
        #pragma unroll
        for (int j = 0; j < 4; ++j) fj[j] = __shfl(scl, lg*4 + j);
        #pragma unroll
        for (int nf = 0; nf < 4; ++nf)
            #pragma unroll
            for (int j = 0; j < 4; ++j) acc[nf][j] *= fj[j];

        // --- O += P·V (P hi/lo x V hi: 3-term) ---
        const char* vhb = (const char*)&vbh[cur][0];
        const char* vlb = (const char*)&vbl[cur][0];
        #pragma unroll
        for (int ks = 0; ks < 2; ++ks) {
            const int poff = lx*128 + ((ks*64 + lg*16) ^ ((lx&1)<<6) ^ ((lx&2)<<4));
            const short8 pah = *(const short8*)((const char*)&pbh[w][0] + poff);
            const short8 pal = *(const short8*)((const char*)&pbl[w][0] + poff);
            #pragma unroll
            for (int nf = 0; nf < 4; ++nf) {
                const int row = nf*16 + lx;
                const int off = row*128 + ((ks*64 + lg*16) ^ ((row&1)<<6) ^ ((row&2)<<4));
                const short8 vh = *(const short8*)(vhb + off);
                const short8 vl = *(const short8*)(vlb + off);
                acc[nf] = MFMA(pah, vh, acc[nf]);
                acc[nf] = MFMA(pah, vl, acc[nf]);
                acc[nf] = MFMA(pal, vh, acc[nf]);
            }
        }

        if (t < SEQ/64 - 1) stage_write(cur ^ 1);
        __syncthreads();
    }

    // epilogue: divide by l, split-store attention output
    float linv[4];
    #pragma unroll
    for (int j = 0; j < 4; ++j) linv[j] = 1.0f / __shfl(l_st, lg*4 + j);
    #pragma unroll
    for (int nf = 0; nf < 4; ++nf) {
        const int c = h*HD + nf*16 + lx;
        #pragma unroll
        for (int j = 0; j < 4; ++j) {
            const size_t tok = (size_t)b*SEQ + qblk + w*16 + lg*4 + j;
            const float o = acc[nf][j] * linv[j];
            const unsigned short hi = f2bf(o);
            AOh[tok*DIM + c] = hi;
            AOl[tok*DIM + c] = f2bf(o - bf2f(hi));
        }
    }
}

// ---------------------------------------------------------------------------
extern "C" void kernel_launch(void* const* d_in, const int* in_sizes, int n_in,
                              void* d_out, int out_size, void* d_ws, size_t ws_size,
                              hipStream_t stream)
{
    const float* x    = (const float*)d_in[0];
    const float* mask = (const float*)d_in[1];
    const float* fc   = (const float*)d_in[2];
    const float* fs   = (const float*)d_in[3];
    const float* wq   = (const float*)d_in[4];
    const float* bq   = (const float*)d_in[5];
    const float* wk   = (const float*)d_in[6];
    const float* bk   = (const float*)d_in[7];
    const float* wv   = (const float*)d_in[8];
    const float* bv   = (const float*)d_in[9];
    const float* wo   = (const float*)d_in[10];
    float* out = (float*)d_out;

    const size_t MB = 1024*1024;
    char* ws = (char*)d_ws;
    unsigned short* Xh  = (unsigned short*)(ws + 0*MB);
    unsigned short* Xl  = (unsigned short*)(ws + 8*MB);
    unsigned short* WTh = (unsigned short*)(ws + 16*MB);   // 4 planes x 2MB (q,k,v,o)
    unsigned short* WTl = (unsigned short*)(ws + 24*MB);
    unsigned short* Qh  = (unsigned short*)(ws + 32*MB);
    unsigned short* Ql  = (unsigned short*)(ws + 40*MB);
    unsigned short* Kh  = (unsigned short*)(ws + 48*MB);
    unsigned short* Kl  = (unsigned short*)(ws + 56*MB);
    unsigned short* Vth = (unsigned short*)(ws + 64*MB);
    unsigned short* Vtl = (unsigned short*)(ws + 72*MB);
    unsigned short* AOh = Xh;   // reuse after QKV GEMM consumed X planes
    unsigned short* AOl = Xl;

    const size_t WP = (size_t)DIM * DIM;  // weight plane elements

    splitx_kernel<<<(ROWS*DIM)/4/256, 256, 0, stream>>>(x, Xh, Xl);
    splitw_kernel<<<dim3(16, 16, 4), 256, 0, stream>>>(wq, wk, wv, wo, WTh, WTl);

    gemm3_kernel<0><<<dim3(8, 32, 3), 256, 0, stream>>>(
        Xh, Xl,
        WTh, WTl, WTh + WP, WTl + WP, WTh + 2*WP, WTl + 2*WP,
        bq, bk, bv, fc, fs,
        Qh, Ql, Kh, Kl, Vth, Vtl, nullptr);

    attn_kernel<<<dim3(SEQ/128, NH, BATCH), 512, 0, stream>>>(
        Qh, Ql, Kh, Kl, Vth, Vtl, mask, AOh, AOl);

    gemm3_kernel<1><<<dim3(8, 32, 1), 256, 0, stream>>>(
        AOh, AOl,
        WTh + 3*WP, WTl + 3*WP, nullptr, nullptr, nullptr, nullptr,
        nullptr, nullptr, nullptr, fc, fs,
        nullptr, nullptr, nullptr, nullptr, nullptr, nullptr, out);
    (void)in_sizes; (void)n_in; (void)out_size; (void)ws_size;
}